// Round 1
// baseline (438.959 us; speedup 1.0000x reference)
//
#include <hip/hip_runtime.h>

#define B_   16
#define L_   4096
#define D_   512
#define C_   256          // output chunk per thread
#define H_   192          // warm-up halo; |lambda|^192 ~ 2e-8 (pole radius 0.9117)
#define NC_  16           // L_/C_

#define SZ_ ((size_t)B_ * L_ * D_)

static_assert(NC_ * C_ == L_, "chunking must tile L");
static_assert((H_ / 8) % 2 == 0 && (C_ / 8) % 2 == 0, "double-buffer pairing");

// ---------------------------------------------------------------------------
// filtfilt via truncated-halo chunks (no inter-chunk scan):
//   forward:  y[t] = bx[t] + A00*y[t-1] + A01*y[t-2]
//   each chunk warms up H_ steps from zero state (exact seed for chunk 0:
//   y[-1]=y[-2]=bx[0]); truncation error ~ 0.9117^H_ ≈ 2e-8 << tolerance.
//   backward symmetric with exact seed at t=L-1 (y'[L]=y'[L+1]=bx'[L-1]).
// Loads double-buffered in groups of 8 to keep ~8 loads in flight per wave.
// ---------------------------------------------------------------------------

__global__ __launch_bounds__(256) void k_fwd(const float* __restrict__ x,
                                             const float* __restrict__ bc,
                                             const float* __restrict__ am,
                                             float* __restrict__ f) {
  int g = blockIdx.x * 256 + threadIdx.x;
  int d = g & (D_ - 1);
  int ci = (g >> 9) & (NC_ - 1);
  int b = g >> 13;
  float b0 = bc[0], b1 = bc[1], b2 = bc[2];
  float A00 = am[0], A01 = am[1];
  const float* xp = x + (size_t)b * L_ * D_ + d;
  float* fo = f + (size_t)b * L_ * D_ + d;
  int l0 = ci * C_;

  float xm1, xm2, y1, y2;
  float va[8], vb[8], fv[8];

#define LD8(dst, tb)                                               \
  _Pragma("unroll") for (int u = 0; u < 8; ++u)                    \
      (dst)[u] = xp[(size_t)((tb) + u) * D_];

#define STEP8(src)                                                 \
  _Pragma("unroll") for (int u = 0; u < 8; ++u) {                  \
    float bx = b0 * (src)[u] + b1 * xm1 + b2 * xm2;                \
    float yy = bx + A00 * y1 + A01 * y2;                           \
    xm2 = xm1; xm1 = (src)[u]; y2 = y1; y1 = yy;                   \
    fv[u] = yy;                                                    \
  }

#define ST8(tb)                                                    \
  _Pragma("unroll") for (int u = 0; u < 8; ++u)                    \
      fo[(size_t)((tb) + u) * D_] = fv[u];

  if (ci == 0) {
    // exact boundary seed: y[-1] = y[-2] = bx[0], x[-1] = x[-2] = x[0]
    float x0 = xp[0];
    xm1 = x0; xm2 = x0;
    float bx0 = (b0 + b1 + b2) * x0;
    y1 = bx0; y2 = bx0;
  } else {
    // zero-state warm-up over [l0-H_, l0)
    const int ls = l0 - H_;
    xm1 = xp[(size_t)(ls - 1) * D_];
    xm2 = xp[(size_t)(ls - 2) * D_];
    y1 = 0.f; y2 = 0.f;
    LD8(va, ls);
#pragma unroll 1
    for (int gg = 0; gg < H_ / 8; gg += 2) {
      LD8(vb, ls + (gg + 1) * 8);
      STEP8(va);
      if (gg + 2 < H_ / 8) LD8(va, ls + (gg + 2) * 8);
      STEP8(vb);
    }
  }
  // output region [l0, l0+C_): store f
  LD8(va, l0);
#pragma unroll 1
  for (int gg = 0; gg < C_ / 8; gg += 2) {
    LD8(vb, l0 + (gg + 1) * 8);
    STEP8(va);
    ST8(l0 + gg * 8);
    if (gg + 2 < C_ / 8) LD8(va, l0 + (gg + 2) * 8);
    STEP8(vb);
    ST8(l0 + (gg + 1) * 8);
  }
#undef LD8
#undef STEP8
#undef ST8
}

// FUSED=true : o0 = seas, o1 = trend (reads x, writes both, nontemporal)
// FUSED=false: o0 = z destination (plan-2 staging), x/o1 unused
template <bool FUSED>
__global__ __launch_bounds__(256) void k_bwd(const float* __restrict__ x,
                                             const float* __restrict__ bc,
                                             const float* __restrict__ am,
                                             const float* __restrict__ f,
                                             float* __restrict__ o0,
                                             float* __restrict__ o1) {
  int g = blockIdx.x * 256 + threadIdx.x;
  int d = g & (D_ - 1);
  int ci = (g >> 9) & (NC_ - 1);
  int b = g >> 13;
  float b0 = bc[0], b1 = bc[1], b2 = bc[2];
  float A00 = am[0], A01 = am[1];
  const float* fi = f + (size_t)b * L_ * D_ + d;
  const float* xp = x + (size_t)b * L_ * D_ + d;
  float* s0p = o0 + (size_t)b * L_ * D_ + d;
  float* s1p = FUSED ? (o1 + (size_t)b * L_ * D_ + d) : o0;
  int l0 = ci * C_;

  float fp1, fp2, z1, z2;
  float va[8], vb[8], xa[8], xc[8], zv[8];

#define LD8R(dst, tb)                                              \
  _Pragma("unroll") for (int u = 0; u < 8; ++u)                    \
      (dst)[u] = fi[(size_t)((tb) - u) * D_];

#define LD8XR(dst, tb)                                             \
  _Pragma("unroll") for (int u = 0; u < 8; ++u)                    \
      (dst)[u] = xp[(size_t)((tb) - u) * D_];

#define STEP8R(src)                                                \
  _Pragma("unroll") for (int u = 0; u < 8; ++u) {                  \
    float bx = b0 * (src)[u] + b1 * fp1 + b2 * fp2;                \
    float zz = bx + A00 * z1 + A01 * z2;                           \
    fp2 = fp1; fp1 = (src)[u]; z2 = z1; z1 = zz;                   \
    zv[u] = zz;                                                    \
  }

#define ST8R(tb, xsrc)                                             \
  _Pragma("unroll") for (int u = 0; u < 8; ++u) {                  \
    size_t o = (size_t)((tb) - u) * D_;                            \
    if (FUSED) {                                                   \
      __builtin_nontemporal_store(zv[u], s0p + o);                 \
      __builtin_nontemporal_store((xsrc)[u] - zv[u], s1p + o);     \
    } else {                                                       \
      s0p[o] = zv[u];                                              \
    }                                                              \
  }

  if (ci == NC_ - 1) {
    // exact boundary seed: y'[L] = y'[L+1] = bx'[L-1] = (b0+b1+b2)*f[L-1]
    float fl = fi[(size_t)(L_ - 1) * D_];
    fp1 = fl; fp2 = fl;
    float c = (b0 + b1 + b2) * fl;
    z1 = c; z2 = c;
  } else {
    // zero-state warm-down over (l0+C_-1+H_ .. l0+C_]
    const int hs = l0 + C_ - 1 + H_;   // max: L-65 for ci=NC_-2, in range
    fp1 = fi[(size_t)(hs + 1) * D_];
    fp2 = fi[(size_t)(hs + 2) * D_];
    z1 = 0.f; z2 = 0.f;
    LD8R(va, hs);
#pragma unroll 1
    for (int gg = 0; gg < H_ / 8; gg += 2) {
      LD8R(vb, hs - (gg + 1) * 8);
      STEP8R(va);
      if (gg + 2 < H_ / 8) LD8R(va, hs - (gg + 2) * 8);
      STEP8R(vb);
    }
  }
  // output region t = l0+C_-1 .. l0
  const int ts = l0 + C_ - 1;
  LD8R(va, ts);
  if (FUSED) LD8XR(xa, ts);
#pragma unroll 1
  for (int gg = 0; gg < C_ / 8; gg += 2) {
    LD8R(vb, ts - (gg + 1) * 8);
    if (FUSED) LD8XR(xc, ts - (gg + 1) * 8);
    STEP8R(va);
    ST8R(ts - gg * 8, xa);
    if (gg + 2 < C_ / 8) {
      LD8R(va, ts - (gg + 2) * 8);
      if (FUSED) LD8XR(xa, ts - (gg + 2) * 8);
    }
    STEP8R(vb);
    ST8R(ts - (gg + 1) * 8, xc);
  }
#undef LD8R
#undef LD8XR
#undef STEP8R
#undef ST8R
}

// plan-2 fixup: trend currently holds z (seas values); split into seas/trend.
// In-place per element -> race-free.
__global__ __launch_bounds__(256) void k_split(const float* __restrict__ x,
                                               float* __restrict__ seas,
                                               float* __restrict__ trend) {
  size_t n4 = SZ_ / 4;
  size_t idx = (size_t)blockIdx.x * 256 + threadIdx.x;
  size_t stride = (size_t)gridDim.x * 256;
  const float4* x4 = (const float4*)x;
  float4* s4 = (float4*)seas;
  float4* t4 = (float4*)trend;
  for (size_t k = idx; k < n4; k += stride) {
    float4 zv = t4[k];
    float4 xv = x4[k];
    float4 tv;
    tv.x = xv.x - zv.x; tv.y = xv.y - zv.y;
    tv.z = xv.z - zv.z; tv.w = xv.w - zv.w;
    s4[k] = zv;
    t4[k] = tv;
  }
}

extern "C" void kernel_launch(void* const* d_in, const int* in_sizes, int n_in,
                              void* d_out, int out_size, void* d_ws, size_t ws_size,
                              hipStream_t stream) {
  const float* x  = (const float*)d_in[0];
  const float* bc = (const float*)d_in[1];
  const float* am = (const float*)d_in[2];
  float* outp  = (float*)d_out;
  float* seas  = outp;
  float* trend = outp + SZ_;

  dim3 blk(256);
  int grid = (int)(B_ * NC_ * D_ / 256);   // 512 blocks

  if (ws_size >= SZ_ * sizeof(float)) {
    // plan 1: f staged in workspace (128 MiB)
    float* f = (float*)d_ws;
    k_fwd<<<grid, blk, 0, stream>>>(x, bc, am, f);
    k_bwd<true><<<grid, blk, 0, stream>>>(x, bc, am, f, seas, trend);
  } else {
    // plan 2: stage f in seas half, z in trend half, then split.
    // k_bwd<false> reads seas (f) beyond its own chunk but writes only trend,
    // so no cross-block race; k_split is element-wise in-place.
    k_fwd<<<grid, blk, 0, stream>>>(x, bc, am, seas);
    k_bwd<false><<<grid, blk, 0, stream>>>(x, bc, am, seas, trend, nullptr);
    k_split<<<2048, blk, 0, stream>>>(x, seas, trend);
  }
}

// Round 2
// 422.878 us; speedup vs baseline: 1.0380x; 1.0380x over previous
//
#include <hip/hip_runtime.h>

#define B_   16
#define L_   4096
#define D_   512
#define W_   256          // D_/2 float2 columns
#define C_   256          // output chunk per thread (t-direction)
#define H_   96           // warm-up halo: 0.9117^96 ~ 1.4e-4, << tolerance
#define NC_  16           // L_/C_

#define SZ_ ((size_t)B_ * L_ * D_)

static_assert(NC_ * C_ == L_, "chunking must tile L");
static_assert((H_ / 8) % 2 == 0 && (C_ / 8) % 2 == 0, "double-buffer pairing");

typedef float fv2 __attribute__((ext_vector_type(2)));

// ---------------------------------------------------------------------------
// filtfilt via truncated-halo chunks (no inter-chunk scan):
//   forward:  y[t] = bx[t] + A00*y[t-1] + A01*y[t-2]
//   chunks warm up H_ steps from zero state (chunk 0 uses the exact seed
//   y[-1]=y[-2]=bx[0]); truncation error ~1.4e-4, invisible vs the 0.03
//   fp32-reference error floor (R0 exact scan and R1 H=192 both absmax
//   0.03125).
//   backward symmetric, exact seed at t=L-1 (y'[L]=y'[L+1]=bx'[L-1]).
// float2 lanes: 512 B per wave load instruction; double-buffered 8-deep
// batches keep 32 KB/CU of loads in flight (~3.5x latency-BW product).
// 256 blocks = 1 block/CU.
// ---------------------------------------------------------------------------

__global__ __launch_bounds__(256) void k_fwd(const float* __restrict__ xf,
                                             const float* __restrict__ bc,
                                             const float* __restrict__ am,
                                             float* __restrict__ ff) {
  int g = blockIdx.x * 256 + threadIdx.x;
  int d = g & (W_ - 1);
  int ci = (g >> 8) & (NC_ - 1);
  int b = g >> 12;
  float b0 = bc[0], b1 = bc[1], b2 = bc[2];
  float A00 = am[0], A01 = am[1];
  const fv2* xp = (const fv2*)xf + (size_t)b * L_ * W_ + d;
  fv2* fo = (fv2*)ff + (size_t)b * L_ * W_ + d;
  int l0 = ci * C_;

  fv2 xm1, xm2, y1, y2;
  fv2 va[8], vb[8], fv[8];

#define LD8(dst, tb)                                               \
  _Pragma("unroll") for (int u = 0; u < 8; ++u)                    \
      (dst)[u] = xp[(size_t)((tb) + u) * W_];

#define STEP8(src)                                                 \
  _Pragma("unroll") for (int u = 0; u < 8; ++u) {                  \
    fv2 bx = b0 * (src)[u] + b1 * xm1 + b2 * xm2;                  \
    fv2 yy = bx + A00 * y1 + A01 * y2;                             \
    xm2 = xm1; xm1 = (src)[u]; y2 = y1; y1 = yy;                   \
    fv[u] = yy;                                                    \
  }

#define ST8(tb)                                                    \
  _Pragma("unroll") for (int u = 0; u < 8; ++u)                    \
      fo[(size_t)((tb) + u) * W_] = fv[u];

  if (ci == 0) {
    // exact boundary seed: y[-1] = y[-2] = bx[0], x[-1] = x[-2] = x[0]
    fv2 x0 = xp[0];
    xm1 = x0; xm2 = x0;
    fv2 bx0 = (b0 + b1 + b2) * x0;
    y1 = bx0; y2 = bx0;
  } else {
    // zero-state warm-up over [l0-H_, l0)
    const int ls = l0 - H_;
    xm1 = xp[(size_t)(ls - 1) * W_];
    xm2 = xp[(size_t)(ls - 2) * W_];
    y1 = 0.f; y2 = 0.f;
    LD8(va, ls);
#pragma unroll 1
    for (int gg = 0; gg < H_ / 8; gg += 2) {
      LD8(vb, ls + (gg + 1) * 8);
      STEP8(va);
      if (gg + 2 < H_ / 8) LD8(va, ls + (gg + 2) * 8);
      STEP8(vb);
    }
  }
  // output region [l0, l0+C_): store f (cacheable -- re-read by k_bwd, fits L3)
  LD8(va, l0);
#pragma unroll 1
  for (int gg = 0; gg < C_ / 8; gg += 2) {
    LD8(vb, l0 + (gg + 1) * 8);
    STEP8(va);
    ST8(l0 + gg * 8);
    if (gg + 2 < C_ / 8) LD8(va, l0 + (gg + 2) * 8);
    STEP8(vb);
    ST8(l0 + (gg + 1) * 8);
  }
#undef LD8
#undef STEP8
#undef ST8
}

// FUSED=true : o0 = seas, o1 = trend (reads x, writes both, nontemporal)
// FUSED=false: o0 = z destination (plan-2 staging), x/o1 unused
template <bool FUSED>
__global__ __launch_bounds__(256) void k_bwd(const float* __restrict__ xf,
                                             const float* __restrict__ bc,
                                             const float* __restrict__ am,
                                             const float* __restrict__ ff,
                                             float* __restrict__ o0,
                                             float* __restrict__ o1) {
  int g = blockIdx.x * 256 + threadIdx.x;
  int d = g & (W_ - 1);
  int ci = (g >> 8) & (NC_ - 1);
  int b = g >> 12;
  float b0 = bc[0], b1 = bc[1], b2 = bc[2];
  float A00 = am[0], A01 = am[1];
  const fv2* fi = (const fv2*)ff + (size_t)b * L_ * W_ + d;
  const fv2* xp = (const fv2*)xf + (size_t)b * L_ * W_ + d;
  fv2* s0p = (fv2*)o0 + (size_t)b * L_ * W_ + d;
  fv2* s1p = FUSED ? ((fv2*)o1 + (size_t)b * L_ * W_ + d) : (fv2*)o0;
  int l0 = ci * C_;

  fv2 fp1, fp2, z1, z2;
  fv2 va[8], vb[8], xa[8], xc[8], zv[8];

#define LD8R(dst, tb)                                              \
  _Pragma("unroll") for (int u = 0; u < 8; ++u)                    \
      (dst)[u] = fi[(size_t)((tb) - u) * W_];

#define LD8XR(dst, tb)                                             \
  _Pragma("unroll") for (int u = 0; u < 8; ++u)                    \
      (dst)[u] = xp[(size_t)((tb) - u) * W_];

#define STEP8R(src)                                                \
  _Pragma("unroll") for (int u = 0; u < 8; ++u) {                  \
    fv2 bx = b0 * (src)[u] + b1 * fp1 + b2 * fp2;                  \
    fv2 zz = bx + A00 * z1 + A01 * z2;                             \
    fp2 = fp1; fp1 = (src)[u]; z2 = z1; z1 = zz;                   \
    zv[u] = zz;                                                    \
  }

#define ST8R(tb, xsrc)                                             \
  _Pragma("unroll") for (int u = 0; u < 8; ++u) {                  \
    size_t o = (size_t)((tb) - u) * W_;                            \
    if (FUSED) {                                                   \
      __builtin_nontemporal_store(zv[u], s0p + o);                 \
      __builtin_nontemporal_store((xsrc)[u] - zv[u], s1p + o);     \
    } else {                                                       \
      s0p[o] = zv[u];                                              \
    }                                                              \
  }

  if (ci == NC_ - 1) {
    // exact boundary seed: y'[L] = y'[L+1] = bx'[L-1] = (b0+b1+b2)*f[L-1]
    fv2 fl = fi[(size_t)(L_ - 1) * W_];
    fp1 = fl; fp2 = fl;
    fv2 c = (b0 + b1 + b2) * fl;
    z1 = c; z2 = c;
  } else {
    // zero-state warm-down over (l0+C_-1+H_ .. l0+C_]
    const int hs = l0 + C_ - 1 + H_;   // max ci=NC_-2: hs+2 = L_-159, in range
    fp1 = fi[(size_t)(hs + 1) * W_];
    fp2 = fi[(size_t)(hs + 2) * W_];
    z1 = 0.f; z2 = 0.f;
    LD8R(va, hs);
#pragma unroll 1
    for (int gg = 0; gg < H_ / 8; gg += 2) {
      LD8R(vb, hs - (gg + 1) * 8);
      STEP8R(va);
      if (gg + 2 < H_ / 8) LD8R(va, hs - (gg + 2) * 8);
      STEP8R(vb);
    }
  }
  // output region t = l0+C_-1 .. l0
  const int ts = l0 + C_ - 1;
  LD8R(va, ts);
  if (FUSED) LD8XR(xa, ts);
#pragma unroll 1
  for (int gg = 0; gg < C_ / 8; gg += 2) {
    LD8R(vb, ts - (gg + 1) * 8);
    if (FUSED) LD8XR(xc, ts - (gg + 1) * 8);
    STEP8R(va);
    ST8R(ts - gg * 8, xa);
    if (gg + 2 < C_ / 8) {
      LD8R(va, ts - (gg + 2) * 8);
      if (FUSED) LD8XR(xa, ts - (gg + 2) * 8);
    }
    STEP8R(vb);
    ST8R(ts - (gg + 1) * 8, xc);
  }
#undef LD8R
#undef LD8XR
#undef STEP8R
#undef ST8R
}

// plan-2 fixup: trend currently holds z (seas values); split into seas/trend.
// In-place per element -> race-free.
__global__ __launch_bounds__(256) void k_split(const float* __restrict__ x,
                                               float* __restrict__ seas,
                                               float* __restrict__ trend) {
  size_t n4 = SZ_ / 4;
  size_t idx = (size_t)blockIdx.x * 256 + threadIdx.x;
  size_t stride = (size_t)gridDim.x * 256;
  const float4* x4 = (const float4*)x;
  float4* s4 = (float4*)seas;
  float4* t4 = (float4*)trend;
  for (size_t k = idx; k < n4; k += stride) {
    float4 zv = t4[k];
    float4 xv = x4[k];
    float4 tv;
    tv.x = xv.x - zv.x; tv.y = xv.y - zv.y;
    tv.z = xv.z - zv.z; tv.w = xv.w - zv.w;
    s4[k] = zv;
    t4[k] = tv;
  }
}

extern "C" void kernel_launch(void* const* d_in, const int* in_sizes, int n_in,
                              void* d_out, int out_size, void* d_ws, size_t ws_size,
                              hipStream_t stream) {
  const float* x  = (const float*)d_in[0];
  const float* bc = (const float*)d_in[1];
  const float* am = (const float*)d_in[2];
  float* outp  = (float*)d_out;
  float* seas  = outp;
  float* trend = outp + SZ_;

  dim3 blk(256);
  int grid = (int)((size_t)B_ * NC_ * W_ / 256);   // 256 blocks = 1/CU

  if (ws_size >= SZ_ * sizeof(float)) {
    // plan 1: f staged in workspace (128 MiB)
    float* f = (float*)d_ws;
    k_fwd<<<grid, blk, 0, stream>>>(x, bc, am, f);
    k_bwd<true><<<grid, blk, 0, stream>>>(x, bc, am, f, seas, trend);
  } else {
    // plan 2: stage f in seas half, z in trend half, then split.
    // k_bwd<false> reads seas (f) beyond its own chunk but writes only trend,
    // so no cross-block race; k_split is element-wise in-place.
    k_fwd<<<grid, blk, 0, stream>>>(x, bc, am, seas);
    k_bwd<false><<<grid, blk, 0, stream>>>(x, bc, am, seas, trend, nullptr);
    k_split<<<2048, blk, 0, stream>>>(x, seas, trend);
  }
}